// Round 7
// baseline (3811.515 us; speedup 1.0000x reference)
//
#include <hip/hip_runtime.h>
#include <hip/hip_bf16.h>
#include <math.h>

#define B_ 2
#define S_ 1024
#define D_ 1024
#define H_ 16
#define DK_ 64
#define L_ 4
#define FF_ 4096
#define V_ 32000
#define NT (B_*S_)   // 2048 tokens

typedef __attribute__((ext_vector_type(8))) short short8v;
typedef __attribute__((ext_vector_type(4))) float floatx4;
typedef __hip_bfloat16 bf16;

__device__ inline float b2f(unsigned short u) {
  unsigned v = ((unsigned)u) << 16;
  float f; __builtin_memcpy(&f, &v, 4); return f;
}
__device__ inline unsigned short f2bu(float f) {
  bf16 h = __float2bfloat16(f);
  unsigned short u; __builtin_memcpy(&u, &h, 2); return u;
}

// ---------------- embed: x = emb[ids] * sqrt(D) (f32) ----------------
__global__ __launch_bounds__(256) void k_embed(const int* __restrict__ ids,
    const float* __restrict__ emb, float* __restrict__ x) {
  int i = blockIdx.x*256 + threadIdx.x;
  if (i >= NT*D_) return;
  int tok = i >> 10;
  int d = i & 1023;
  x[i] = emb[(size_t)ids[tok]*D_ + d] * 32.0f;
}

// ---------------- rmsnorm: o(bf16) = w * x / sqrt(mean(x^2)+1e-8) ----------
__global__ __launch_bounds__(256) void k_rms(const float* __restrict__ x,
    const float* __restrict__ w, bf16* __restrict__ o) {
  int row = blockIdx.x;
  const float* xr = x + (size_t)row*D_;
  float s = 0.f;
  for (int d = threadIdx.x; d < D_; d += 256) { float v = xr[d]; s += v*v; }
  for (int off = 32; off; off >>= 1) s += __shfl_down(s, off);
  __shared__ float red[4];
  __shared__ float inv_s;
  int wid = threadIdx.x >> 6;
  if ((threadIdx.x & 63) == 0) red[wid] = s;
  __syncthreads();
  if (threadIdx.x == 0) {
    float t = red[0]+red[1]+red[2]+red[3];
    inv_s = 1.0f / sqrtf(t * (1.0f/D_) + 1e-8f);
  }
  __syncthreads();
  float inv = inv_s;
  bf16* orow = o + (size_t)row*D_;
  for (int d = threadIdx.x; d < D_; d += 256) orow[d] = __float2bfloat16(w[d]*xr[d]*inv);
}

// ------- transpose+cast: src[K,N] f32 -> dst[N,K] bf16, 64x64, z=layer -----
__global__ __launch_bounds__(256) void k_transpose_cast(const float* __restrict__ src0,
    bf16* __restrict__ dst0, int K, int N, size_t src_stride, size_t dst_stride) {
  const float* src = src0 + blockIdx.z * src_stride;
  bf16* dst = dst0 + blockIdx.z * dst_stride;
  __shared__ float t[64][65];
  int k0 = blockIdx.y*64, n0 = blockIdx.x*64;
  int r  = threadIdx.x >> 4;        // 0..15
  int c4 = (threadIdx.x & 15)*4;    // 0..60
  #pragma unroll
  for (int i = 0; i < 4; ++i) {
    float4 v = *(const float4*)(src + (size_t)(k0 + r + i*16)*N + n0 + c4);
    t[r+i*16][c4] = v.x; t[r+i*16][c4+1] = v.y;
    t[r+i*16][c4+2] = v.z; t[r+i*16][c4+3] = v.w;
  }
  __syncthreads();
  int nn = threadIdx.x >> 2;        // 0..63
  int kc = threadIdx.x & 3;         // 0..3
  #pragma unroll
  for (int i = 0; i < 4; ++i) {
    int kk = kc*4 + i*16;
    ushort4 o;
    o.x = f2bu(t[kk][nn]);   o.y = f2bu(t[kk+1][nn]);
    o.z = f2bu(t[kk+2][nn]); o.w = f2bu(t[kk+3][nn]);
    *(ushort4*)(dst + (size_t)(n0+nn)*K + k0 + kk) = o;
  }
}

// ---------------- cast f32 -> bf16, 4/thread ----------------
__global__ __launch_bounds__(256) void k_cast4(const float* __restrict__ s,
    bf16* __restrict__ d, int n4) {
  int i = blockIdx.x*256 + threadIdx.x;
  if (i >= n4) return;
  float4 v = ((const float4*)s)[i];
  ushort4 o;
  o.x = f2bu(v.x); o.y = f2bu(v.y); o.z = f2bu(v.z); o.w = f2bu(v.w);
  ((ushort4*)d)[i] = o;
}

// ---------------- MFMA GEMM (m97 structure): 128x128, BK=32, 4 waves -------
// EPI: 2 = rope factor on first 2048 cols.
template<int EPI, bool OUTBF>
__global__ __launch_bounds__(256) void k_mfma_gemm_bt(
    const bf16* __restrict__ A, const bf16* __restrict__ Bt,
    const void* __restrict__ aux, void* __restrict__ Cout,
    int M, int N, int K) {
  const int NM = M >> 7, NN = N >> 7;
  const int wg = blockIdx.x;
  const int grp = wg >> 3, xcd = wg & 7;
  const int mi = grp % NM;
  const int ni = xcd + 8*(grp / NM);
  if (ni >= NN) return;
  const int bm = mi * 128;
  const int bn = ni * 128;

  __shared__ bf16 As[128*32];
  __shared__ bf16 Bs[128*32];
  const int tid  = threadIdx.x;
  const int lane = tid & 63;
  const int wave = tid >> 6;
  const int wm = (wave >> 1) * 64;
  const int wn = (wave & 1) * 64;

  floatx4 acc[4][4] = {};

  for (int k0 = 0; k0 < K; k0 += 32) {
    #pragma unroll
    for (int c = 0; c < 2; ++c) {
      int e = (c*256 + tid) * 8;
      int row = e >> 5, col = e & 31;
      const bf16* ga = A  + (size_t)(bm + row)*K + k0 + col;
      const bf16* gb = Bt + (size_t)(bn + row)*K + k0 + col;
      int ldsoff = (c*256 + wave*64) * 8;
      __builtin_amdgcn_global_load_lds(
        (const __attribute__((address_space(1))) void*)ga,
        (__attribute__((address_space(3))) void*)(As + ldsoff), 16, 0, 0);
      __builtin_amdgcn_global_load_lds(
        (const __attribute__((address_space(1))) void*)gb,
        (__attribute__((address_space(3))) void*)(Bs + ldsoff), 16, 0, 0);
    }
    __syncthreads();
    const int r = lane & 15, kc = lane >> 4;
    short8v a[4], b[4];
    #pragma unroll
    for (int i = 0; i < 4; ++i) {
      a[i] = *(const short8v*)(As + (size_t)(wm + i*16 + r)*32 + kc*8);
      b[i] = *(const short8v*)(Bs + (size_t)(wn + i*16 + r)*32 + kc*8);
    }
    #pragma unroll
    for (int i = 0; i < 4; ++i)
      #pragma unroll
      for (int j = 0; j < 4; ++j)
        acc[i][j] = __builtin_amdgcn_mfma_f32_16x16x32_bf16(a[i], b[j], acc[i][j], 0, 0, 0);
    __syncthreads();
  }

  const int cn = lane & 15, rq = lane >> 4;
  #pragma unroll
  for (int i=0;i<4;i++) {
    #pragma unroll
    for (int j=0;j<4;j++) {
      const int gcol = bn + wn + j*16 + cn;
      float freq = 0.f;
      if constexpr (EPI==2) {
        if (gcol < 2048)
          freq = expf((float)(gcol & 31) * -0.28782313662425574f); // -ln(1e4)/32
      }
      #pragma unroll
      for (int rr=0; rr<4; ++rr) {
        const int grow = bm + wm + i*16 + rq*4 + rr;
        const size_t off = (size_t)grow*N + gcol;
        float v = acc[i][j][rr];
        if constexpr (EPI==1) v += ((const float*)aux)[off];
        if constexpr (EPI==2) {
          if (gcol < 2048) {
            float sn, cs;
            sincosf((float)(grow & 1023) * freq, &sn, &cs);
            v *= (cs + sn);
          }
        }
        if constexpr (OUTBF) ((bf16*)Cout)[off] = __float2bfloat16(v);
        else                 ((float*)Cout)[off] = v;
      }
    }
  }
}

static inline int remap_grid(int M, int N) {
  int NM = M >> 7, NN = N >> 7;
  int NN8 = (NN + 7) & ~7;
  return NM * NN8;
}

// ---------------- 64x128-tile MFMA GEMM for narrow-N (o-proj / down-proj) --
__global__ __launch_bounds__(256) void k_gemm_64(
    const bf16* __restrict__ A, const bf16* __restrict__ Bt,
    const float* __restrict__ res, float* __restrict__ C,
    int M, int N, int K, int lda) {
  const int NN = N >> 7;
  const int nwg = gridDim.x;
  const int id = (blockIdx.x & 7)*(nwg >> 3) + (blockIdx.x >> 3);
  const int mi = id / NN, ni = id % NN;
  const int bm = mi << 6, bn = ni << 7;

  __shared__ bf16 As[64*32];
  __shared__ bf16 Bs[128*32];
  const int tid  = threadIdx.x;
  const int lane = tid & 63;
  const int wave = tid >> 6;
  const int wm = (wave >> 1) * 32;
  const int wn = (wave & 1) * 64;

  floatx4 acc[2][4] = {};

  for (int k0 = 0; k0 < K; k0 += 32) {
    {
      int row = tid >> 2, col = (tid & 3)*8;
      const bf16* ga = A + (size_t)(bm + row)*lda + k0 + col;
      __builtin_amdgcn_global_load_lds(
        (const __attribute__((address_space(1))) void*)ga,
        (__attribute__((address_space(3))) void*)(As + wave*512), 16, 0, 0);
    }
    #pragma unroll
    for (int c = 0; c < 2; ++c) {
      int i = c*256 + tid;
      int row = i >> 2, col = (i & 3)*8;
      const bf16* gb = Bt + (size_t)(bn + row)*K + k0 + col;
      __builtin_amdgcn_global_load_lds(
        (const __attribute__((address_space(1))) void*)gb,
        (__attribute__((address_space(3))) void*)(Bs + (c*256 + wave*64)*8), 16, 0, 0);
    }
    __syncthreads();
    const int r = lane & 15, kc = lane >> 4;
    short8v a[2], b[4];
    #pragma unroll
    for (int i = 0; i < 2; ++i)
      a[i] = *(const short8v*)(As + (size_t)(wm + i*16 + r)*32 + kc*8);
    #pragma unroll
    for (int j = 0; j < 4; ++j)
      b[j] = *(const short8v*)(Bs + (size_t)(wn + j*16 + r)*32 + kc*8);
    #pragma unroll
    for (int i = 0; i < 2; ++i)
      #pragma unroll
      for (int j = 0; j < 4; ++j)
        acc[i][j] = __builtin_amdgcn_mfma_f32_16x16x32_bf16(a[i], b[j], acc[i][j], 0, 0, 0);
    __syncthreads();
  }

  const int cn = lane & 15, rq = lane >> 4;
  #pragma unroll
  for (int i = 0; i < 2; ++i) {
    #pragma unroll
    for (int j = 0; j < 4; ++j) {
      #pragma unroll
      for (int rr = 0; rr < 4; ++rr) {
        int grow = bm + wm + i*16 + rq*4 + rr;
        int gcol = bn + wn + j*16 + cn;
        size_t off = (size_t)grow*N + gcol;
        C[off] = acc[i][j][rr] + res[off];
      }
    }
  }
}

// ---------------- 256x256 MFMA GEMM, 2-phase pipeline, double buffer -------
// Minimum 2-phase recipe: STAGE(buf^1,t+1) BEFORE ds_read+MFMA, one
// vmcnt(0)+s_barrier per K-tile. LDS 64 KB -> 2 blocks/CU (inter-block TLP).
template<bool OUTBF>
__global__ __launch_bounds__(512, 4) void k_gemm256(
    const bf16* __restrict__ A, const bf16* __restrict__ Bt,
    void* __restrict__ C, int M, int N, int K) {
  const int NM = M >> 8;
  const int nwg = gridDim.x;
  const int id = (blockIdx.x & 7)*(nwg >> 3) + (blockIdx.x >> 3);
  const int mi = id % NM, ni = id / NM;
  const int bm = mi << 8, bn = ni << 8;

  __shared__ bf16 As2[2][256*32];
  __shared__ bf16 Bs2[2][256*32];

  const int tid  = threadIdx.x;
  const int lane = tid & 63;
  const int wave = tid >> 6;
  const int wr = wave >> 2;
  const int wc = wave & 3;
  const int fr = lane & 15;
  const int kc = lane >> 4;

  floatx4 acc[8][4] = {};
  const int ntk = K >> 5;

  auto stage = [&](int kt, int slot) {
    const bf16* Ab = A  + (size_t)bm*K + kt*32;
    const bf16* Bb = Bt + (size_t)bn*K + kt*32;
    #pragma unroll
    for (int c = 0; c < 2; ++c) {
      int i = c*512 + tid;
      int row = i >> 2, sl = i & 3;
      int gcol = (sl ^ ((row >> 1) & 3)) * 8;
      int ldsoff = (c*512 + wave*64) * 8;
      __builtin_amdgcn_global_load_lds(
        (const __attribute__((address_space(1))) void*)(Ab + (size_t)row*K + gcol),
        (__attribute__((address_space(3))) void*)(&As2[slot][ldsoff]), 16, 0, 0);
      __builtin_amdgcn_global_load_lds(
        (const __attribute__((address_space(1))) void*)(Bb + (size_t)row*K + gcol),
        (__attribute__((address_space(3))) void*)(&Bs2[slot][ldsoff]), 16, 0, 0);
    }
  };

  stage(0, 0);
  asm volatile("s_waitcnt vmcnt(0)" ::: "memory");
  __builtin_amdgcn_s_barrier();

  int cur = 0;
  for (int t = 0; t < ntk; ++t) {
    if (t + 1 < ntk) stage(t + 1, cur ^ 1);

    const bf16* Ab = As2[cur];
    const bf16* Bb = Bs2[cur];
    short8v a[8], b[4];
    #pragma unroll
    for (int f = 0; f < 8; ++f) {
      int r = wr*128 + f*16 + fr;
      int sl = kc ^ ((r >> 1) & 3);
      a[f] = *(const short8v*)(Ab + r*32 + sl*8);
    }
    #pragma unroll
    for (int f = 0; f < 4; ++f) {
      int r = wc*64 + f*16 + fr;
      int sl = kc ^ ((r >> 1) & 3);
      b[f] = *(const short8v*)(Bb + r*32 + sl*8);
    }
    __builtin_amdgcn_s_setprio(1);
    #pragma unroll
    for (int f = 0; f < 8; ++f)
      #pragma unroll
      for (int j = 0; j < 4; ++j)
        acc[f][j] = __builtin_amdgcn_mfma_f32_16x16x32_bf16(a[f], b[j], acc[f][j], 0, 0, 0);
    __builtin_amdgcn_s_setprio(0);

    asm volatile("s_waitcnt vmcnt(0)" ::: "memory");
    __builtin_amdgcn_s_barrier();
    cur ^= 1;
  }

  const int cn = lane & 15, rq = lane >> 4;
  #pragma unroll
  for (int f = 0; f < 8; ++f) {
    #pragma unroll
    for (int j = 0; j < 4; ++j) {
      #pragma unroll
      for (int rr = 0; rr < 4; ++rr) {
        int row = bm + wr*128 + f*16 + rq*4 + rr;
        int col = bn + wc*64 + j*16 + cn;
        size_t off = (size_t)row*N + col;
        if constexpr (OUTBF) ((bf16*)C)[off] = __float2bfloat16(acc[f][j][rr]);
        else                 ((float*)C)[off] = acc[f][j][rr];
      }
    }
  }
}

// ------- in-place silu-mul over fused gu buffer: gu[:, :4096] = silu(g)*u ---
__global__ __launch_bounds__(256) void k_silumul_gu(bf16* __restrict__ gu) {
  int i = blockIdx.x*256 + threadIdx.x;     // over NT*4096/8
  if (i >= NT*512) return;
  int row = i >> 9;
  int c8 = (i & 511)*8;
  unsigned short* p = (unsigned short*)gu + (size_t)row*8192 + c8;
  short8v g = *(const short8v*)p;
  short8v u = *(const short8v*)(p + 4096);
  short8v o;
  #pragma unroll
  for (int j = 0; j < 8; ++j) {
    float gf = b2f((unsigned short)g[j]);
    float uf = b2f((unsigned short)u[j]);
    o[j] = (short)f2bu(gf / (1.0f + expf(-gf)) * uf);
  }
  *(short8v*)p = o;
}

// ---------------- flash attention: MFMA, online softmax --------------------
__global__ __launch_bounds__(256) void k_fattn(const bf16* __restrict__ qkvb,
    bf16* __restrict__ outb) {
  const unsigned short* qkv = (const unsigned short*)qkvb;
  const int qt = 15 - blockIdx.x;
  const int h = blockIdx.y, b = blockIdx.z;
  const int tid = threadIdx.x, lane = tid & 63, w = tid >> 6;
  const int g = lane >> 4, qn = lane & 15;

  __shared__ unsigned short Ks[64*64];
  __shared__ unsigned short Vt[64*64];
  __shared__ unsigned short Ps[4*16*64];

  const int q0 = qt * 64;
  const int qw0 = q0 + w*16;

  short8v qf[2];
  {
    const unsigned short* qp = qkv + ((size_t)(b*S_ + qw0 + qn))*3072 + h*DK_ + g*8;
    qf[0] = *(const short8v*)qp;
    qf[1] = *(const short8v*)(qp + 32);
  }

  floatx4 o_acc[4] = {};
  float m_run = -1e30f, l_run = 0.f;

  const int ntile = qt + 1;
  for (int it = 0; it < ntile; ++it) {
    const int t0 = it*64;

    {
      const int trow = w*8 + (lane>>3);
      const int d16 = (lane&7) ^ (trow&7);
      #pragma unroll
      for (int c = 0; c < 2; ++c) {
        const unsigned short* gk = qkv + ((size_t)(b*S_ + t0 + c*32 + trow))*3072
                                   + 1024 + h*DK_ + d16*8;
        __builtin_amdgcn_global_load_lds(
          (const __attribute__((address_space(1))) void*)gk,
          (__attribute__((address_space(3))) void*)(Ks + c*2048 + w*512), 16, 0, 0);
      }
    }
    #pragma unroll
    for (int c = 0; c < 2; ++c) {
      int idx = c*256 + tid;
      int t = idx >> 3;
      int d0 = (idx & 7)*8;
      short8v vv = *(const short8v*)(qkv + ((size_t)(b*S_ + t0 + t))*3072 + 2048 + h*DK_ + d0);
      #pragma unroll
      for (int jj = 0; jj < 8; ++jj) {
        int d = d0 + jj;
        int slot = ((t>>3) ^ (d&7) ^ ((d>>3)&7)) & 7;
        Vt[d*64 + slot*8 + (t&7)] = (unsigned short)vv[jj];
      }
    }
    __syncthreads();

    floatx4 st[4];
    #pragma unroll
    for (int f = 0; f < 4; ++f) {
      st[f] = (floatx4){0.f,0.f,0.f,0.f};
      int t = f*16 + qn;
      #pragma unroll
      for (int ks = 0; ks < 2; ++ks) {
        int slot = ((ks*4 + g) ^ (t&7)) & 7;
        short8v kf = *(const short8v*)(Ks + t*64 + slot*8);
        st[f] = __builtin_amdgcn_mfma_f32_16x16x32_bf16(kf, qf[ks], st[f], 0,0,0);
      }
    }

    const bool diag = (it == qt);
    float sc[4][4];
    #pragma unroll
    for (int f = 0; f < 4; ++f)
      #pragma unroll
      for (int r = 0; r < 4; ++r) {
        float v = st[f][r]*0.125f;
        if (diag) {
          int tl = f*16 + g*4 + r;
          if (tl > w*16 + qn) v = -1e30f;
        }
        sc[f][r] = v;
      }
    float mx = -1e30f;
    #pragma unroll
    for (int f = 0; f < 4; ++f)
      #pragma unroll
      for (int r = 0; r < 4; ++r) mx = fmaxf(mx, sc[f][r]);
    mx = fmaxf(mx, __shfl_xor(mx, 16));
    mx = fmaxf(mx, __shfl_xor(mx, 32));
    float m_new = fmaxf(m_run, mx);
    float corr = __expf(m_run - m_new);
    m_run = m_new;
    float ls = 0.f;
    #pragma unroll
    for (int f = 0; f < 4; ++f)
      #pragma unroll
      for (int r = 0; r < 4; ++r) {
        float p = __expf(sc[f][r] - m_new);
        sc[f][r] = p;
        ls += p;
      }
    ls += __shfl_xor(ls, 16);
    ls += __shfl_xor(ls, 32);
    l_run = l_run*corr + ls;

    unsigned short* Pw = Ps + w*1024;
    #pragma unroll
    for (int f = 0; f < 4; ++f) {
      unsigned int lo = (unsigned int)f2bu(sc[f][0]) | ((unsigned int)f2bu(sc[f][1]) << 16);
      unsigned int hi = (unsigned int)f2bu(sc[f][2]) | ((unsigned int)f2bu(sc[f][3]) << 16);
      int c16 = f*2 + (g>>1);
      int slot = (c16 ^ (qn&7)) & 7;
      *(uint2*)((char*)Pw + qn*128 + slot*16 + (g&1)*8) = make_uint2(lo, hi);
    }

    #pragma unroll
    for (int r = 0; r < 4; ++r) {
      float cr = __shfl(corr, g*4 + r);
      #pragma unroll
      for (int fd = 0; fd < 4; ++fd) o_acc[fd][r] *= cr;
    }

    short8v pf[2];
    #pragma unroll
    for (int ks = 0; ks < 2; ++ks) {
      int slot = ((ks*4 + g) ^ (qn&7)) & 7;
      pf[ks] = *(const short8v*)(Pw + qn*64 + slot*8);
    }
    #pragma unroll
    for (int fd = 0; fd < 4; ++fd) {
      int d = fd*16 + qn;
      #pragma unroll
      for (int ks = 0; ks < 2; ++ks) {
        int slot = ((ks*4 + g) ^ (d&7) ^ ((d>>3)&7)) & 7;
        short8v vf = *(const short8v*)(Vt + d*64 + slot*8);
        o_acc[fd] = __builtin_amdgcn_mfma_f32_16x16x32_bf16(pf[ks], vf, o_acc[fd], 0,0,0);
      }
    }
    __syncthreads();
  }

  float linv = 1.0f / l_run;
  #pragma unroll
  for (int r = 0; r < 4; ++r) {
    float li = __shfl(linv, g*4 + r);
    int row = qw0 + g*4 + r;
    bf16* op = outb + (size_t)(b*S_ + row)*D_ + h*DK_ + qn;
    #pragma unroll
    for (int fd = 0; fd < 4; ++fd)
      op[fd*16] = __float2bfloat16(o_acc[fd][r] * li);
  }
}

extern "C" void kernel_launch(void* const* d_in, const int* in_sizes, int n_in,
                              void* d_out, int out_size, void* d_ws, size_t ws_size,
                              hipStream_t stream) {
  (void)in_sizes; (void)n_in; (void)out_size; (void)ws_size;
  const int*   ids  = (const int*)d_in[0];
  const float* emb  = (const float*)d_in[1];
  const float* wqkv = (const float*)d_in[2];
  const float* wo   = (const float*)d_in[3];
  const float* n1   = (const float*)d_in[4];
  const float* n2   = (const float*)d_in[5];
  const float* wg   = (const float*)d_in[6];
  const float* wu   = (const float*)d_in[7];
  const float* wd   = (const float*)d_in[8];
  const float* fnw  = (const float*)d_in[9];
  float* out = (float*)d_out;

  char* ws = (char*)d_ws;
  float* x      = (float*)ws;                                   ws += (size_t)NT*D_*4;
  bf16*  nx_bf  = (bf16*)ws;                                    ws += (size_t)NT*D_*2;
  bf16*  att_bf = (bf16*)ws;                                    ws += (size_t)NT*D_*2;
  bf16*  shared = (bf16*)ws;                                    ws += (size_t)NT*8192*2;
  bf16*  emb_bf = (bf16*)ws;                                    ws += (size_t)V_*D_*2;
  bf16*  qkv_bf = shared;                 // NT*3D, dead before gu written
  bf16*  gu     = shared;                 // NT*8192 (g | u), silu'd in place

  bf16* wsc = (bf16*)d_out;
  bf16* wqkv_t = wsc;                                  // L*3D*D
  bf16* wo_t   = wqkv_t + (size_t)L_*3*D_*D_;          // L*D*D
  bf16* wgu_t  = wo_t   + (size_t)L_*D_*D_;            // L*8192*1024 (gate|up)
  bf16* wd_t   = wgu_t  + (size_t)L_*2*D_*FF_;         // L*D*FF

  dim3 blk(256);

  {
    dim3 gq(3*D_/64, D_/64, L_);
    k_transpose_cast<<<gq, blk, 0, stream>>>(wqkv, wqkv_t, D_, 3*D_,
        (size_t)D_*3*D_, (size_t)3*D_*D_);
    dim3 go(D_/64, D_/64, L_);
    k_transpose_cast<<<go, blk, 0, stream>>>(wo, wo_t, D_, D_,
        (size_t)D_*D_, (size_t)D_*D_);
    dim3 gg(FF_/64, D_/64, L_);
    k_transpose_cast<<<gg, blk, 0, stream>>>(wg, wgu_t, D_, FF_,
        (size_t)D_*FF_, (size_t)2*D_*FF_);
    k_transpose_cast<<<gg, blk, 0, stream>>>(wu, wgu_t + (size_t)FF_*D_, D_, FF_,
        (size_t)D_*FF_, (size_t)2*D_*FF_);
    dim3 gdn(D_/64, FF_/64, L_);
    k_transpose_cast<<<gdn, blk, 0, stream>>>(wd, wd_t, FF_, D_,
        (size_t)FF_*D_, (size_t)D_*FF_);
  }
  k_cast4<<<(V_*D_/4 + 255)/256, blk, 0, stream>>>(emb, emb_bf, V_*D_/4);

  k_embed<<<(NT*D_+255)/256, blk, 0, stream>>>(ids, emb, x);

  for (int l = 0; l < L_; ++l) {
    k_rms<<<NT, blk, 0, stream>>>(x, n1 + (size_t)l*D_, nx_bf);
    k_mfma_gemm_bt<2,true><<<remap_grid(NT,3*D_), blk, 0, stream>>>(
        nx_bf, wqkv_t + (size_t)l*3*D_*D_, nullptr, qkv_bf, NT, 3*D_, D_);
    dim3 gattn(16, H_, B_);
    k_fattn<<<gattn, blk, 0, stream>>>(qkv_bf, att_bf);
    k_gemm_64<<<(NT/64)*(D_/128), blk, 0, stream>>>(
        att_bf, wo_t + (size_t)l*D_*D_, x, x, NT, D_, D_, D_);
    k_rms<<<NT, blk, 0, stream>>>(x, n2 + (size_t)l*D_, nx_bf);
    k_gemm256<true><<<(NT/256)*(2*FF_/256), dim3(512), 0, stream>>>(
        nx_bf, wgu_t + (size_t)l*2*D_*FF_, gu, NT, 2*FF_, D_);
    k_silumul_gu<<<(NT*512 + 255)/256, blk, 0, stream>>>(gu);
    k_gemm_64<<<(NT/64)*(D_/128), blk, 0, stream>>>(
        gu, wd_t + (size_t)l*D_*FF_, x, x, NT, D_, FF_, 2*FF_);
  }
  k_rms<<<NT, blk, 0, stream>>>(x, fnw, nx_bf);
  k_gemm256<false><<<(NT/256)*(V_/256), dim3(512), 0, stream>>>(
      nx_bf, emb_bf, out, NT, V_, D_);
}

// Round 8
// 1325.798 us; speedup vs baseline: 2.8749x; 2.8749x over previous
//
#include <hip/hip_runtime.h>
#include <hip/hip_bf16.h>
#include <math.h>

#define B_ 2
#define S_ 1024
#define D_ 1024
#define H_ 16
#define DK_ 64
#define L_ 4
#define FF_ 4096
#define V_ 32000
#define NT (B_*S_)   // 2048 tokens

typedef __attribute__((ext_vector_type(8))) short short8v;
typedef __attribute__((ext_vector_type(4))) float floatx4;
typedef __hip_bfloat16 bf16;

__device__ inline float b2f(unsigned short u) {
  unsigned v = ((unsigned)u) << 16;
  float f; __builtin_memcpy(&f, &v, 4); return f;
}
__device__ inline unsigned short f2bu(float f) {
  bf16 h = __float2bfloat16(f);
  unsigned short u; __builtin_memcpy(&u, &h, 2); return u;
}

// ---------------- embed: x = emb[ids] * sqrt(D) (f32) ----------------
__global__ __launch_bounds__(256) void k_embed(const int* __restrict__ ids,
    const float* __restrict__ emb, float* __restrict__ x) {
  int i = blockIdx.x*256 + threadIdx.x;
  if (i >= NT*D_) return;
  int tok = i >> 10;
  int d = i & 1023;
  x[i] = emb[(size_t)ids[tok]*D_ + d] * 32.0f;
}

// ---------------- rmsnorm: o(bf16) = w * x / sqrt(mean(x^2)+1e-8) ----------
__global__ __launch_bounds__(256) void k_rms(const float* __restrict__ x,
    const float* __restrict__ w, bf16* __restrict__ o) {
  int row = blockIdx.x;
  const float* xr = x + (size_t)row*D_;
  float s = 0.f;
  for (int d = threadIdx.x; d < D_; d += 256) { float v = xr[d]; s += v*v; }
  for (int off = 32; off; off >>= 1) s += __shfl_down(s, off);
  __shared__ float red[4];
  __shared__ float inv_s;
  int wid = threadIdx.x >> 6;
  if ((threadIdx.x & 63) == 0) red[wid] = s;
  __syncthreads();
  if (threadIdx.x == 0) {
    float t = red[0]+red[1]+red[2]+red[3];
    inv_s = 1.0f / sqrtf(t * (1.0f/D_) + 1e-8f);
  }
  __syncthreads();
  float inv = inv_s;
  bf16* orow = o + (size_t)row*D_;
  for (int d = threadIdx.x; d < D_; d += 256) orow[d] = __float2bfloat16(w[d]*xr[d]*inv);
}

// ------- transpose+cast: src[K,N] f32 -> dst[N,K] bf16, 64x64, z=layer -----
__global__ __launch_bounds__(256) void k_transpose_cast(const float* __restrict__ src0,
    bf16* __restrict__ dst0, int K, int N, size_t src_stride, size_t dst_stride) {
  const float* src = src0 + blockIdx.z * src_stride;
  bf16* dst = dst0 + blockIdx.z * dst_stride;
  __shared__ float t[64][65];
  int k0 = blockIdx.y*64, n0 = blockIdx.x*64;
  int r  = threadIdx.x >> 4;        // 0..15
  int c4 = (threadIdx.x & 15)*4;    // 0..60
  #pragma unroll
  for (int i = 0; i < 4; ++i) {
    float4 v = *(const float4*)(src + (size_t)(k0 + r + i*16)*N + n0 + c4);
    t[r+i*16][c4] = v.x; t[r+i*16][c4+1] = v.y;
    t[r+i*16][c4+2] = v.z; t[r+i*16][c4+3] = v.w;
  }
  __syncthreads();
  int nn = threadIdx.x >> 2;        // 0..63
  int kc = threadIdx.x & 3;         // 0..3
  #pragma unroll
  for (int i = 0; i < 4; ++i) {
    int kk = kc*4 + i*16;
    ushort4 o;
    o.x = f2bu(t[kk][nn]);   o.y = f2bu(t[kk+1][nn]);
    o.z = f2bu(t[kk+2][nn]); o.w = f2bu(t[kk+3][nn]);
    *(ushort4*)(dst + (size_t)(n0+nn)*K + k0 + kk) = o;
  }
}

// ---------------- cast f32 -> bf16, 4/thread ----------------
__global__ __launch_bounds__(256) void k_cast4(const float* __restrict__ s,
    bf16* __restrict__ d, int n4) {
  int i = blockIdx.x*256 + threadIdx.x;
  if (i >= n4) return;
  float4 v = ((const float4*)s)[i];
  ushort4 o;
  o.x = f2bu(v.x); o.y = f2bu(v.y); o.z = f2bu(v.z); o.w = f2bu(v.w);
  ((ushort4*)d)[i] = o;
}

// ---------------- MFMA GEMM (m97 structure): 128x128, BK=32, 4 waves -------
// EPI: 2 = rope factor on first 2048 cols.
template<int EPI, bool OUTBF>
__global__ __launch_bounds__(256) void k_mfma_gemm_bt(
    const bf16* __restrict__ A, const bf16* __restrict__ Bt,
    const void* __restrict__ aux, void* __restrict__ Cout,
    int M, int N, int K) {
  const int NM = M >> 7, NN = N >> 7;
  const int wg = blockIdx.x;
  const int grp = wg >> 3, xcd = wg & 7;
  const int mi = grp % NM;
  const int ni = xcd + 8*(grp / NM);
  if (ni >= NN) return;
  const int bm = mi * 128;
  const int bn = ni * 128;

  __shared__ bf16 As[128*32];
  __shared__ bf16 Bs[128*32];
  const int tid  = threadIdx.x;
  const int lane = tid & 63;
  const int wave = tid >> 6;
  const int wm = (wave >> 1) * 64;
  const int wn = (wave & 1) * 64;

  floatx4 acc[4][4] = {};

  for (int k0 = 0; k0 < K; k0 += 32) {
    #pragma unroll
    for (int c = 0; c < 2; ++c) {
      int e = (c*256 + tid) * 8;
      int row = e >> 5, col = e & 31;
      const bf16* ga = A  + (size_t)(bm + row)*K + k0 + col;
      const bf16* gb = Bt + (size_t)(bn + row)*K + k0 + col;
      int ldsoff = (c*256 + wave*64) * 8;
      __builtin_amdgcn_global_load_lds(
        (const __attribute__((address_space(1))) void*)ga,
        (__attribute__((address_space(3))) void*)(As + ldsoff), 16, 0, 0);
      __builtin_amdgcn_global_load_lds(
        (const __attribute__((address_space(1))) void*)gb,
        (__attribute__((address_space(3))) void*)(Bs + ldsoff), 16, 0, 0);
    }
    __syncthreads();
    const int r = lane & 15, kc = lane >> 4;
    short8v a[4], b[4];
    #pragma unroll
    for (int i = 0; i < 4; ++i) {
      a[i] = *(const short8v*)(As + (size_t)(wm + i*16 + r)*32 + kc*8);
      b[i] = *(const short8v*)(Bs + (size_t)(wn + i*16 + r)*32 + kc*8);
    }
    #pragma unroll
    for (int i = 0; i < 4; ++i)
      #pragma unroll
      for (int j = 0; j < 4; ++j)
        acc[i][j] = __builtin_amdgcn_mfma_f32_16x16x32_bf16(a[i], b[j], acc[i][j], 0, 0, 0);
    __syncthreads();
  }

  const int cn = lane & 15, rq = lane >> 4;
  #pragma unroll
  for (int i=0;i<4;i++) {
    #pragma unroll
    for (int j=0;j<4;j++) {
      const int gcol = bn + wn + j*16 + cn;
      float freq = 0.f;
      if constexpr (EPI==2) {
        if (gcol < 2048)
          freq = expf((float)(gcol & 31) * -0.28782313662425574f); // -ln(1e4)/32
      }
      #pragma unroll
      for (int rr=0; rr<4; ++rr) {
        const int grow = bm + wm + i*16 + rq*4 + rr;
        const size_t off = (size_t)grow*N + gcol;
        float v = acc[i][j][rr];
        if constexpr (EPI==1) v += ((const float*)aux)[off];
        if constexpr (EPI==2) {
          if (gcol < 2048) {
            float sn, cs;
            sincosf((float)(grow & 1023) * freq, &sn, &cs);
            v *= (cs + sn);
          }
        }
        if constexpr (OUTBF) ((bf16*)Cout)[off] = __float2bfloat16(v);
        else                 ((float*)Cout)[off] = v;
      }
    }
  }
}

static inline int remap_grid(int M, int N) {
  int NM = M >> 7, NN = N >> 7;
  int NN8 = (NN + 7) & ~7;
  return NM * NN8;
}

// ---------------- 64x128-tile MFMA GEMM for narrow-N (o-proj / down-proj) --
__global__ __launch_bounds__(256) void k_gemm_64(
    const bf16* __restrict__ A, const bf16* __restrict__ Bt,
    const float* __restrict__ res, float* __restrict__ C,
    int M, int N, int K, int lda) {
  const int NN = N >> 7;
  const int nwg = gridDim.x;
  const int id = (blockIdx.x & 7)*(nwg >> 3) + (blockIdx.x >> 3);
  const int mi = id / NN, ni = id % NN;
  const int bm = mi << 6, bn = ni << 7;

  __shared__ bf16 As[64*32];
  __shared__ bf16 Bs[128*32];
  const int tid  = threadIdx.x;
  const int lane = tid & 63;
  const int wave = tid >> 6;
  const int wm = (wave >> 1) * 32;
  const int wn = (wave & 1) * 64;

  floatx4 acc[2][4] = {};

  for (int k0 = 0; k0 < K; k0 += 32) {
    {
      int row = tid >> 2, col = (tid & 3)*8;
      const bf16* ga = A + (size_t)(bm + row)*lda + k0 + col;
      __builtin_amdgcn_global_load_lds(
        (const __attribute__((address_space(1))) void*)ga,
        (__attribute__((address_space(3))) void*)(As + wave*512), 16, 0, 0);
    }
    #pragma unroll
    for (int c = 0; c < 2; ++c) {
      int i = c*256 + tid;
      int row = i >> 2, col = (i & 3)*8;
      const bf16* gb = Bt + (size_t)(bn + row)*K + k0 + col;
      __builtin_amdgcn_global_load_lds(
        (const __attribute__((address_space(1))) void*)gb,
        (__attribute__((address_space(3))) void*)(Bs + (c*256 + wave*64)*8), 16, 0, 0);
    }
    __syncthreads();
    const int r = lane & 15, kc = lane >> 4;
    short8v a[2], b[4];
    #pragma unroll
    for (int i = 0; i < 2; ++i)
      a[i] = *(const short8v*)(As + (size_t)(wm + i*16 + r)*32 + kc*8);
    #pragma unroll
    for (int j = 0; j < 4; ++j)
      b[j] = *(const short8v*)(Bs + (size_t)(wn + j*16 + r)*32 + kc*8);
    #pragma unroll
    for (int i = 0; i < 2; ++i)
      #pragma unroll
      for (int j = 0; j < 4; ++j)
        acc[i][j] = __builtin_amdgcn_mfma_f32_16x16x32_bf16(a[i], b[j], acc[i][j], 0, 0, 0);
    __syncthreads();
  }

  const int cn = lane & 15, rq = lane >> 4;
  #pragma unroll
  for (int i = 0; i < 2; ++i) {
    #pragma unroll
    for (int j = 0; j < 4; ++j) {
      #pragma unroll
      for (int rr = 0; rr < 4; ++rr) {
        int grow = bm + wm + i*16 + rq*4 + rr;
        int gcol = bn + wn + j*16 + cn;
        size_t off = (size_t)grow*N + gcol;
        C[off] = acc[i][j][rr] + res[off];
      }
    }
  }
}

// ---------------- 256x256 pipelined MFMA GEMM (round-5 proven version) -----
// Triple-buffered LDS (96 KB), 2-K-tile prefetch, counted vmcnt(8), raw
// s_barrier. __launch_bounds__(512,2): do NOT raise — (512,4) caps VGPR at
// ~128 and spills the 128-f32 accumulator to scratch (round-7 regression:
// 7.6 GB scratch traffic, MfmaUtil 3.5%).
template<bool OUTBF>
__global__ __launch_bounds__(512, 2) void k_gemm256(
    const bf16* __restrict__ A, const bf16* __restrict__ Bt,
    void* __restrict__ C, int M, int N, int K) {
  const int NM = M >> 8;
  const int nwg = gridDim.x;
  const int id = (blockIdx.x & 7)*(nwg >> 3) + (blockIdx.x >> 3); // chunked XCD
  const int mi = id % NM, ni = id / NM;
  const int bm = mi << 8, bn = ni << 8;

  __shared__ bf16 As3[3][256*32];
  __shared__ bf16 Bs3[3][256*32];

  const int tid  = threadIdx.x;
  const int lane = tid & 63;
  const int wave = tid >> 6;
  const int wr = wave >> 2;
  const int wc = wave & 3;
  const int fr = lane & 15;
  const int kc = lane >> 4;

  floatx4 acc[8][4] = {};
  const int ntk = K >> 5;

  auto stage = [&](int kt, int slot) {
    const bf16* Ab = A  + (size_t)bm*K + kt*32;
    const bf16* Bb = Bt + (size_t)bn*K + kt*32;
    #pragma unroll
    for (int c = 0; c < 2; ++c) {
      int i = c*512 + tid;
      int row = i >> 2, sl = i & 3;
      int gcol = (sl ^ ((row >> 1) & 3)) * 8;
      int ldsoff = (c*512 + wave*64) * 8;
      __builtin_amdgcn_global_load_lds(
        (const __attribute__((address_space(1))) void*)(Ab + (size_t)row*K + gcol),
        (__attribute__((address_space(3))) void*)(&As3[slot][ldsoff]), 16, 0, 0);
      __builtin_amdgcn_global_load_lds(
        (const __attribute__((address_space(1))) void*)(Bb + (size_t)row*K + gcol),
        (__attribute__((address_space(3))) void*)(&Bs3[slot][ldsoff]), 16, 0, 0);
    }
  };

  stage(0, 0);
  if (ntk > 1) stage(1, 1);

  for (int t = 0; t < ntk; ++t) {
    const int cur = t % 3;
    __builtin_amdgcn_sched_barrier(0);
    __builtin_amdgcn_s_barrier();
    __builtin_amdgcn_sched_barrier(0);
    if (t + 2 < ntk) {
      stage(t + 2, (t + 2) % 3);
      __builtin_amdgcn_sched_barrier(0);
      asm volatile("s_waitcnt vmcnt(8)" ::: "memory");
    } else if (t + 1 < ntk) {
      asm volatile("s_waitcnt vmcnt(4)" ::: "memory");
    } else {
      asm volatile("s_waitcnt vmcnt(0)" ::: "memory");
    }
    __builtin_amdgcn_sched_barrier(0);
    __builtin_amdgcn_s_barrier();
    __builtin_amdgcn_sched_barrier(0);

    const bf16* Ab = As3[cur];
    const bf16* Bb = Bs3[cur];
    short8v a[8], b[4];
    #pragma unroll
    for (int f = 0; f < 8; ++f) {
      int r = wr*128 + f*16 + fr;
      int sl = kc ^ ((r >> 1) & 3);
      a[f] = *(const short8v*)(Ab + r*32 + sl*8);
    }
    #pragma unroll
    for (int f = 0; f < 4; ++f) {
      int r = wc*64 + f*16 + fr;
      int sl = kc ^ ((r >> 1) & 3);
      b[f] = *(const short8v*)(Bb + r*32 + sl*8);
    }
    __builtin_amdgcn_s_setprio(1);
    #pragma unroll
    for (int f = 0; f < 8; ++f)
      #pragma unroll
      for (int j = 0; j < 4; ++j)
        acc[f][j] = __builtin_amdgcn_mfma_f32_16x16x32_bf16(a[f], b[j], acc[f][j], 0, 0, 0);
    __builtin_amdgcn_s_setprio(0);
  }

  const int cn = lane & 15, rq = lane >> 4;
  #pragma unroll
  for (int f = 0; f < 8; ++f) {
    #pragma unroll
    for (int j = 0; j < 4; ++j) {
      #pragma unroll
      for (int rr = 0; rr < 4; ++rr) {
        int row = bm + wr*128 + f*16 + rq*4 + rr;
        int col = bn + wc*64 + j*16 + cn;
        size_t off = (size_t)row*N + col;
        if constexpr (OUTBF) ((bf16*)C)[off] = __float2bfloat16(acc[f][j][rr]);
        else                 ((float*)C)[off] = acc[f][j][rr];
      }
    }
  }
}

// ------- in-place silu-mul over fused gu buffer: gu[:, :4096] = silu(g)*u ---
__global__ __launch_bounds__(256) void k_silumul_gu(bf16* __restrict__ gu) {
  int i = blockIdx.x*256 + threadIdx.x;     // over NT*4096/8
  if (i >= NT*512) return;
  int row = i >> 9;
  int c8 = (i & 511)*8;
  unsigned short* p = (unsigned short*)gu + (size_t)row*8192 + c8;
  short8v g = *(const short8v*)p;
  short8v u = *(const short8v*)(p + 4096);
  short8v o;
  #pragma unroll
  for (int j = 0; j < 8; ++j) {
    float gf = b2f((unsigned short)g[j]);
    float uf = b2f((unsigned short)u[j]);
    o[j] = (short)f2bu(gf / (1.0f + expf(-gf)) * uf);
  }
  *(short8v*)p = o;
}

// ---------------- flash attention: MFMA, online softmax --------------------
__global__ __launch_bounds__(256) void k_fattn(const bf16* __restrict__ qkvb,
    bf16* __restrict__ outb) {
  const unsigned short* qkv = (const unsigned short*)qkvb;
  const int qt = 15 - blockIdx.x;
  const int h = blockIdx.y, b = blockIdx.z;
  const int tid = threadIdx.x, lane = tid & 63, w = tid >> 6;
  const int g = lane >> 4, qn = lane & 15;

  __shared__ unsigned short Ks[64*64];
  __shared__ unsigned short Vt[64*64];
  __shared__ unsigned short Ps[4*16*64];

  const int q0 = qt * 64;
  const int qw0 = q0 + w*16;

  short8v qf[2];
  {
    const unsigned short* qp = qkv + ((size_t)(b*S_ + qw0 + qn))*3072 + h*DK_ + g*8;
    qf[0] = *(const short8v*)qp;
    qf[1] = *(const short8v*)(qp + 32);
  }

  floatx4 o_acc[4] = {};
  float m_run = -1e30f, l_run = 0.f;

  const int ntile = qt + 1;
  for (int it = 0; it < ntile; ++it) {
    const int t0 = it*64;

    {
      const int trow = w*8 + (lane>>3);
      const int d16 = (lane&7) ^ (trow&7);
      #pragma unroll
      for (int c = 0; c < 2; ++c) {
        const unsigned short* gk = qkv + ((size_t)(b*S_ + t0 + c*32 + trow))*3072
                                   + 1024 + h*DK_ + d16*8;
        __builtin_amdgcn_global_load_lds(
          (const __attribute__((address_space(1))) void*)gk,
          (__attribute__((address_space(3))) void*)(Ks + c*2048 + w*512), 16, 0, 0);
      }
    }
    #pragma unroll
    for (int c = 0; c < 2; ++c) {
      int idx = c*256 + tid;
      int t = idx >> 3;
      int d0 = (idx & 7)*8;
      short8v vv = *(const short8v*)(qkv + ((size_t)(b*S_ + t0 + t))*3072 + 2048 + h*DK_ + d0);
      #pragma unroll
      for (int jj = 0; jj < 8; ++jj) {
        int d = d0 + jj;
        int slot = ((t>>3) ^ (d&7) ^ ((d>>3)&7)) & 7;
        Vt[d*64 + slot*8 + (t&7)] = (unsigned short)vv[jj];
      }
    }
    __syncthreads();

    floatx4 st[4];
    #pragma unroll
    for (int f = 0; f < 4; ++f) {
      st[f] = (floatx4){0.f,0.f,0.f,0.f};
      int t = f*16 + qn;
      #pragma unroll
      for (int ks = 0; ks < 2; ++ks) {
        int slot = ((ks*4 + g) ^ (t&7)) & 7;
        short8v kf = *(const short8v*)(Ks + t*64 + slot*8);
        st[f] = __builtin_amdgcn_mfma_f32_16x16x32_bf16(kf, qf[ks], st[f], 0,0,0);
      }
    }

    const bool diag = (it == qt);
    float sc[4][4];
    #pragma unroll
    for (int f = 0; f < 4; ++f)
      #pragma unroll
      for (int r = 0; r < 4; ++r) {
        float v = st[f][r]*0.125f;
        if (diag) {
          int tl = f*16 + g*4 + r;
          if (tl > w*16 + qn) v = -1e30f;
        }
        sc[f][r] = v;
      }
    float mx = -1e30f;
    #pragma unroll
    for (int f = 0; f < 4; ++f)
      #pragma unroll
      for (int r = 0; r < 4; ++r) mx = fmaxf(mx, sc[f][r]);
    mx = fmaxf(mx, __shfl_xor(mx, 16));
    mx = fmaxf(mx, __shfl_xor(mx, 32));
    float m_new = fmaxf(m_run, mx);
    float corr = __expf(m_run - m_new);
    m_run = m_new;
    float ls = 0.f;
    #pragma unroll
    for (int f = 0; f < 4; ++f)
      #pragma unroll
      for (int r = 0; r < 4; ++r) {
        float p = __expf(sc[f][r] - m_new);
        sc[f][r] = p;
        ls += p;
      }
    ls += __shfl_xor(ls, 16);
    ls += __shfl_xor(ls, 32);
    l_run = l_run*corr + ls;

    unsigned short* Pw = Ps + w*1024;
    #pragma unroll
    for (int f = 0; f < 4; ++f) {
      unsigned int lo = (unsigned int)f2bu(sc[f][0]) | ((unsigned int)f2bu(sc[f][1]) << 16);
      unsigned int hi = (unsigned int)f2bu(sc[f][2]) | ((unsigned int)f2bu(sc[f][3]) << 16);
      int c16 = f*2 + (g>>1);
      int slot = (c16 ^ (qn&7)) & 7;
      *(uint2*)((char*)Pw + qn*128 + slot*16 + (g&1)*8) = make_uint2(lo, hi);
    }

    #pragma unroll
    for (int r = 0; r < 4; ++r) {
      float cr = __shfl(corr, g*4 + r);
      #pragma unroll
      for (int fd = 0; fd < 4; ++fd) o_acc[fd][r] *= cr;
    }

    short8v pf[2];
    #pragma unroll
    for (int ks = 0; ks < 2; ++ks) {
      int slot = ((ks*4 + g) ^ (qn&7)) & 7;
      pf[ks] = *(const short8v*)(Pw + qn*64 + slot*8);
    }
    #pragma unroll
    for (int fd = 0; fd < 4; ++fd) {
      int d = fd*16 + qn;
      #pragma unroll
      for (int ks = 0; ks < 2; ++ks) {
        int slot = ((ks*4 + g) ^ (d&7) ^ ((d>>3)&7)) & 7;
        short8v vf = *(const short8v*)(Vt + d*64 + slot*8);
        o_acc[fd] = __builtin_amdgcn_mfma_f32_16x16x32_bf16(pf[ks], vf, o_acc[fd], 0,0,0);
      }
    }
    __syncthreads();
  }

  float linv = 1.0f / l_run;
  #pragma unroll
  for (int r = 0; r < 4; ++r) {
    float li = __shfl(linv, g*4 + r);
    int row = qw0 + g*4 + r;
    bf16* op = outb + (size_t)(b*S_ + row)*D_ + h*DK_ + qn;
    #pragma unroll
    for (int fd = 0; fd < 4; ++fd)
      op[fd*16] = __float2bfloat16(o_acc[fd][r] * li);
  }
}

extern "C" void kernel_launch(void* const* d_in, const int* in_sizes, int n_in,
                              void* d_out, int out_size, void* d_ws, size_t ws_size,
                              hipStream_t stream) {
  (void)in_sizes; (void)n_in; (void)out_size; (void)ws_size;
  const int*   ids  = (const int*)d_in[0];
  const float* emb  = (const float*)d_in[1];
  const float* wqkv = (const float*)d_in[2];
  const float* wo   = (const float*)d_in[3];
  const float* n1   = (const float*)d_in[4];
  const float* n2   = (const float*)d_in[5];
  const float* wg   = (const float*)d_in[6];
  const float* wu   = (const float*)d_in[7];
  const float* wd   = (const float*)d_in[8];
  const float* fnw  = (const float*)d_in[9];
  float* out = (float*)d_out;

  char* ws = (char*)d_ws;
  float* x      = (float*)ws;                                   ws += (size_t)NT*D_*4;
  bf16*  nx_bf  = (bf16*)ws;                                    ws += (size_t)NT*D_*2;
  bf16*  att_bf = (bf16*)ws;                                    ws += (size_t)NT*D_*2;
  bf16*  shared = (bf16*)ws;                                    ws += (size_t)NT*8192*2;
  bf16*  emb_bf = (bf16*)ws;                                    ws += (size_t)V_*D_*2;
  bf16*  qkv_bf = shared;                 // NT*3D, dead before gu written
  bf16*  gu     = shared;                 // NT*8192 (g | u), silu'd in place

  bf16* wsc = (bf16*)d_out;
  bf16* wqkv_t = wsc;                                  // L*3D*D
  bf16* wo_t   = wqkv_t + (size_t)L_*3*D_*D_;          // L*D*D
  bf16* wgu_t  = wo_t   + (size_t)L_*D_*D_;            // L*8192*1024 (gate|up)
  bf16* wd_t   = wgu_t  + (size_t)L_*2*D_*FF_;         // L*D*FF

  dim3 blk(256);

  {
    dim3 gq(3*D_/64, D_/64, L_);
    k_transpose_cast<<<gq, blk, 0, stream>>>(wqkv, wqkv_t, D_, 3*D_,
        (size_t)D_*3*D_, (size_t)3*D_*D_);
    dim3 go(D_/64, D_/64, L_);
    k_transpose_cast<<<go, blk, 0, stream>>>(wo, wo_t, D_, D_,
        (size_t)D_*D_, (size_t)D_*D_);
    dim3 gg(FF_/64, D_/64, L_);
    k_transpose_cast<<<gg, blk, 0, stream>>>(wg, wgu_t, D_, FF_,
        (size_t)D_*FF_, (size_t)2*D_*FF_);
    k_transpose_cast<<<gg, blk, 0, stream>>>(wu, wgu_t + (size_t)FF_*D_, D_, FF_,
        (size_t)D_*FF_, (size_t)2*D_*FF_);
    dim3 gdn(D_/64, FF_/64, L_);
    k_transpose_cast<<<gdn, blk, 0, stream>>>(wd, wd_t, FF_, D_,
        (size_t)FF_*D_, (size_t)D_*FF_);
  }
  k_cast4<<<(V_*D_/4 + 255)/256, blk, 0, stream>>>(emb, emb_bf, V_*D_/4);

  k_embed<<<(NT*D_+255)/256, blk, 0, stream>>>(ids, emb, x);

  for (int l = 0; l < L_; ++l) {
    k_rms<<<NT, blk, 0, stream>>>(x, n1 + (size_t)l*D_, nx_bf);
    k_mfma_gemm_bt<2,true><<<remap_grid(NT,3*D_), blk, 0, stream>>>(
        nx_bf, wqkv_t + (size_t)l*3*D_*D_, nullptr, qkv_bf, NT, 3*D_, D_);
    dim3 gattn(16, H_, B_);
    k_fattn<<<gattn, blk, 0, stream>>>(qkv_bf, att_bf);
    k_gemm_64<<<(NT/64)*(D_/128), blk, 0, stream>>>(
        att_bf, wo_t + (size_t)l*D_*D_, x, x, NT, D_, D_, D_);
    k_rms<<<NT, blk, 0, stream>>>(x, n2 + (size_t)l*D_, nx_bf);
    k_gemm256<true><<<(NT/256)*(2*FF_/256), dim3(512), 0, stream>>>(
        nx_bf, wgu_t + (size_t)l*2*D_*FF_, gu, NT, 2*FF_, D_);
    k_silumul_gu<<<(NT*512 + 255)/256, blk, 0, stream>>>(gu);
    k_gemm_64<<<(NT/64)*(D_/128), blk, 0, stream>>>(
        gu, wd_t + (size_t)l*D_*FF_, x, x, NT, D_, FF_, 2*FF_);
  }
  k_rms<<<NT, blk, 0, stream>>>(x, fnw, nx_bf);
  k_gemm256<false><<<(NT/256)*(V_/256), dim3(512), 0, stream>>>(
      nx_bf, emb_bf, out, NT, V_, D_);
}

// Round 9
// 1261.808 us; speedup vs baseline: 3.0207x; 1.0507x over previous
//
#include <hip/hip_runtime.h>
#include <hip/hip_bf16.h>
#include <math.h>

#define B_ 2
#define S_ 1024
#define D_ 1024
#define H_ 16
#define DK_ 64
#define L_ 4
#define FF_ 4096
#define V_ 32000
#define NT (B_*S_)   // 2048 tokens

typedef __attribute__((ext_vector_type(8))) short short8v;
typedef __attribute__((ext_vector_type(4))) float floatx4;
typedef __hip_bfloat16 bf16;

__device__ inline float b2f(unsigned short u) {
  unsigned v = ((unsigned)u) << 16;
  float f; __builtin_memcpy(&f, &v, 4); return f;
}
__device__ inline unsigned short f2bu(float f) {
  bf16 h = __float2bfloat16(f);
  unsigned short u; __builtin_memcpy(&u, &h, 2); return u;
}

// ---------------- embed: x = emb[ids] * sqrt(D) (f32) ----------------
__global__ __launch_bounds__(256) void k_embed(const int* __restrict__ ids,
    const float* __restrict__ emb, float* __restrict__ x) {
  int i = blockIdx.x*256 + threadIdx.x;
  if (i >= NT*D_) return;
  int tok = i >> 10;
  int d = i & 1023;
  x[i] = emb[(size_t)ids[tok]*D_ + d] * 32.0f;
}

// ---------------- rmsnorm: o(bf16) = w * x / sqrt(mean(x^2)+1e-8) ----------
__global__ __launch_bounds__(256) void k_rms(const float* __restrict__ x,
    const float* __restrict__ w, bf16* __restrict__ o) {
  int row = blockIdx.x;
  const float* xr = x + (size_t)row*D_;
  float s = 0.f;
  for (int d = threadIdx.x; d < D_; d += 256) { float v = xr[d]; s += v*v; }
  for (int off = 32; off; off >>= 1) s += __shfl_down(s, off);
  __shared__ float red[4];
  __shared__ float inv_s;
  int wid = threadIdx.x >> 6;
  if ((threadIdx.x & 63) == 0) red[wid] = s;
  __syncthreads();
  if (threadIdx.x == 0) {
    float t = red[0]+red[1]+red[2]+red[3];
    inv_s = 1.0f / sqrtf(t * (1.0f/D_) + 1e-8f);
  }
  __syncthreads();
  float inv = inv_s;
  bf16* orow = o + (size_t)row*D_;
  for (int d = threadIdx.x; d < D_; d += 256) orow[d] = __float2bfloat16(w[d]*xr[d]*inv);
}

// ------- transpose+cast: src[K,N] f32 -> dst[N,K] bf16, 64x64, z=layer -----
__global__ __launch_bounds__(256) void k_transpose_cast(const float* __restrict__ src0,
    bf16* __restrict__ dst0, int K, int N, size_t src_stride, size_t dst_stride) {
  const float* src = src0 + blockIdx.z * src_stride;
  bf16* dst = dst0 + blockIdx.z * dst_stride;
  __shared__ float t[64][65];
  int k0 = blockIdx.y*64, n0 = blockIdx.x*64;
  int r  = threadIdx.x >> 4;        // 0..15
  int c4 = (threadIdx.x & 15)*4;    // 0..60
  #pragma unroll
  for (int i = 0; i < 4; ++i) {
    float4 v = *(const float4*)(src + (size_t)(k0 + r + i*16)*N + n0 + c4);
    t[r+i*16][c4] = v.x; t[r+i*16][c4+1] = v.y;
    t[r+i*16][c4+2] = v.z; t[r+i*16][c4+3] = v.w;
  }
  __syncthreads();
  int nn = threadIdx.x >> 2;        // 0..63
  int kc = threadIdx.x & 3;         // 0..3
  #pragma unroll
  for (int i = 0; i < 4; ++i) {
    int kk = kc*4 + i*16;
    ushort4 o;
    o.x = f2bu(t[kk][nn]);   o.y = f2bu(t[kk+1][nn]);
    o.z = f2bu(t[kk+2][nn]); o.w = f2bu(t[kk+3][nn]);
    *(ushort4*)(dst + (size_t)(n0+nn)*K + k0 + kk) = o;
  }
}

// ---------------- cast f32 -> bf16, 4/thread ----------------
__global__ __launch_bounds__(256) void k_cast4(const float* __restrict__ s,
    bf16* __restrict__ d, int n4) {
  int i = blockIdx.x*256 + threadIdx.x;
  if (i >= n4) return;
  float4 v = ((const float4*)s)[i];
  ushort4 o;
  o.x = f2bu(v.x); o.y = f2bu(v.y); o.z = f2bu(v.z); o.w = f2bu(v.w);
  ((ushort4*)d)[i] = o;
}

// ---------------- MFMA GEMM (m97 structure): 128x128, BK=32, 4 waves -------
// EPI: 2 = rope factor on first 2048 cols.
template<int EPI, bool OUTBF>
__global__ __launch_bounds__(256) void k_mfma_gemm_bt(
    const bf16* __restrict__ A, const bf16* __restrict__ Bt,
    const void* __restrict__ aux, void* __restrict__ Cout,
    int M, int N, int K) {
  const int NM = M >> 7, NN = N >> 7;
  const int wg = blockIdx.x;
  const int grp = wg >> 3, xcd = wg & 7;
  const int mi = grp % NM;
  const int ni = xcd + 8*(grp / NM);
  if (ni >= NN) return;
  const int bm = mi * 128;
  const int bn = ni * 128;

  __shared__ bf16 As[128*32];
  __shared__ bf16 Bs[128*32];
  const int tid  = threadIdx.x;
  const int lane = tid & 63;
  const int wave = tid >> 6;
  const int wm = (wave >> 1) * 64;
  const int wn = (wave & 1) * 64;

  floatx4 acc[4][4] = {};

  for (int k0 = 0; k0 < K; k0 += 32) {
    #pragma unroll
    for (int c = 0; c < 2; ++c) {
      int e = (c*256 + tid) * 8;
      int row = e >> 5, col = e & 31;
      const bf16* ga = A  + (size_t)(bm + row)*K + k0 + col;
      const bf16* gb = Bt + (size_t)(bn + row)*K + k0 + col;
      int ldsoff = (c*256 + wave*64) * 8;
      __builtin_amdgcn_global_load_lds(
        (const __attribute__((address_space(1))) void*)ga,
        (__attribute__((address_space(3))) void*)(As + ldsoff), 16, 0, 0);
      __builtin_amdgcn_global_load_lds(
        (const __attribute__((address_space(1))) void*)gb,
        (__attribute__((address_space(3))) void*)(Bs + ldsoff), 16, 0, 0);
    }
    __syncthreads();
    const int r = lane & 15, kc = lane >> 4;
    short8v a[4], b[4];
    #pragma unroll
    for (int i = 0; i < 4; ++i) {
      a[i] = *(const short8v*)(As + (size_t)(wm + i*16 + r)*32 + kc*8);
      b[i] = *(const short8v*)(Bs + (size_t)(wn + i*16 + r)*32 + kc*8);
    }
    #pragma unroll
    for (int i = 0; i < 4; ++i)
      #pragma unroll
      for (int j = 0; j < 4; ++j)
        acc[i][j] = __builtin_amdgcn_mfma_f32_16x16x32_bf16(a[i], b[j], acc[i][j], 0, 0, 0);
    __syncthreads();
  }

  const int cn = lane & 15, rq = lane >> 4;
  #pragma unroll
  for (int i=0;i<4;i++) {
    #pragma unroll
    for (int j=0;j<4;j++) {
      const int gcol = bn + wn + j*16 + cn;
      float freq = 0.f;
      if constexpr (EPI==2) {
        if (gcol < 2048)
          freq = expf((float)(gcol & 31) * -0.28782313662425574f); // -ln(1e4)/32
      }
      #pragma unroll
      for (int rr=0; rr<4; ++rr) {
        const int grow = bm + wm + i*16 + rq*4 + rr;
        const size_t off = (size_t)grow*N + gcol;
        float v = acc[i][j][rr];
        if constexpr (EPI==1) v += ((const float*)aux)[off];
        if constexpr (EPI==2) {
          if (gcol < 2048) {
            float sn, cs;
            sincosf((float)(grow & 1023) * freq, &sn, &cs);
            v *= (cs + sn);
          }
        }
        if constexpr (OUTBF) ((bf16*)Cout)[off] = __float2bfloat16(v);
        else                 ((float*)Cout)[off] = v;
      }
    }
  }
}

static inline int remap_grid(int M, int N) {
  int NM = M >> 7, NN = N >> 7;
  int NN8 = (NN + 7) & ~7;
  return NM * NN8;
}

// ---------------- 64x128-tile MFMA GEMM for narrow-N (o-proj / down-proj) --
__global__ __launch_bounds__(256) void k_gemm_64(
    const bf16* __restrict__ A, const bf16* __restrict__ Bt,
    const float* __restrict__ res, float* __restrict__ C,
    int M, int N, int K, int lda) {
  const int NN = N >> 7;
  const int nwg = gridDim.x;
  const int id = (blockIdx.x & 7)*(nwg >> 3) + (blockIdx.x >> 3);
  const int mi = id / NN, ni = id % NN;
  const int bm = mi << 6, bn = ni << 7;

  __shared__ bf16 As[64*32];
  __shared__ bf16 Bs[128*32];
  const int tid  = threadIdx.x;
  const int lane = tid & 63;
  const int wave = tid >> 6;
  const int wm = (wave >> 1) * 32;
  const int wn = (wave & 1) * 64;

  floatx4 acc[2][4] = {};

  for (int k0 = 0; k0 < K; k0 += 32) {
    {
      int row = tid >> 2, col = (tid & 3)*8;
      const bf16* ga = A + (size_t)(bm + row)*lda + k0 + col;
      __builtin_amdgcn_global_load_lds(
        (const __attribute__((address_space(1))) void*)ga,
        (__attribute__((address_space(3))) void*)(As + wave*512), 16, 0, 0);
    }
    #pragma unroll
    for (int c = 0; c < 2; ++c) {
      int i = c*256 + tid;
      int row = i >> 2, col = (i & 3)*8;
      const bf16* gb = Bt + (size_t)(bn + row)*K + k0 + col;
      __builtin_amdgcn_global_load_lds(
        (const __attribute__((address_space(1))) void*)gb,
        (__attribute__((address_space(3))) void*)(Bs + (c*256 + wave*64)*8), 16, 0, 0);
    }
    __syncthreads();
    const int r = lane & 15, kc = lane >> 4;
    short8v a[2], b[4];
    #pragma unroll
    for (int i = 0; i < 2; ++i)
      a[i] = *(const short8v*)(As + (size_t)(wm + i*16 + r)*32 + kc*8);
    #pragma unroll
    for (int j = 0; j < 4; ++j)
      b[j] = *(const short8v*)(Bs + (size_t)(wn + j*16 + r)*32 + kc*8);
    #pragma unroll
    for (int i = 0; i < 2; ++i)
      #pragma unroll
      for (int j = 0; j < 4; ++j)
        acc[i][j] = __builtin_amdgcn_mfma_f32_16x16x32_bf16(a[i], b[j], acc[i][j], 0, 0, 0);
    __syncthreads();
  }

  const int cn = lane & 15, rq = lane >> 4;
  #pragma unroll
  for (int i = 0; i < 2; ++i) {
    #pragma unroll
    for (int j = 0; j < 4; ++j) {
      #pragma unroll
      for (int rr = 0; rr < 4; ++rr) {
        int grow = bm + wm + i*16 + rq*4 + rr;
        int gcol = bn + wn + j*16 + cn;
        size_t off = (size_t)grow*N + gcol;
        C[off] = acc[i][j][rr] + res[off];
      }
    }
  }
}

// ---------------- 256x256 pipelined MFMA GEMM, 2-phase fine interleave -----
// Triple-buffered LDS (96 KB, 1 block/CU), 2-K-tile prefetch. Per K-tile:
// entry vmcnt(4) (tile t complete, t+1's 4 loads stay in flight across
// barriers — never drained mid-loop), then 2 phases of
// {ds_read subtile ∥ stage half of tile t+2 -> lgkmcnt(0)+sched_barrier
//  (rule #18) -> setprio(1) 16 MFMA setprio(0) -> s_barrier}.
// Phase barriers create wave role-split (2 waves/SIMD alternate MFMA vs
// ds_read/stage). Do NOT raise launch_bounds past (512,2): (512,4) caps
// VGPR at ~128 and spills the accumulator (round-7: 7.6 GB scratch).
template<bool OUTBF>
__global__ __launch_bounds__(512, 2) void k_gemm256(
    const bf16* __restrict__ A, const bf16* __restrict__ Bt,
    void* __restrict__ C, int M, int N, int K) {
  const int NM = M >> 8;
  const int nwg = gridDim.x;
  const int id = (blockIdx.x & 7)*(nwg >> 3) + (blockIdx.x >> 3); // chunked XCD
  const int mi = id % NM, ni = id / NM;
  const int bm = mi << 8, bn = ni << 8;

  __shared__ bf16 As3[3][256*32];
  __shared__ bf16 Bs3[3][256*32];

  const int tid  = threadIdx.x;
  const int lane = tid & 63;
  const int wave = tid >> 6;
  const int wr = wave >> 2;
  const int wc = wave & 3;
  const int fr = lane & 15;
  const int kc = lane >> 4;

  floatx4 acc[8][4] = {};
  const int ntk = K >> 5;

  // one chunk = half of K-tile kt's staging (2 loads/thread: A + B)
  auto stage_chunk = [&](int kt, int slot, int c) {
    const bf16* Ab = A  + (size_t)bm*K + kt*32;
    const bf16* Bb = Bt + (size_t)bn*K + kt*32;
    int i = c*512 + tid;
    int row = i >> 2, sl = i & 3;
    int gcol = (sl ^ ((row >> 1) & 3)) * 8;
    int ldsoff = (c*512 + wave*64) * 8;
    __builtin_amdgcn_global_load_lds(
      (const __attribute__((address_space(1))) void*)(Ab + (size_t)row*K + gcol),
      (__attribute__((address_space(3))) void*)(&As3[slot][ldsoff]), 16, 0, 0);
    __builtin_amdgcn_global_load_lds(
      (const __attribute__((address_space(1))) void*)(Bb + (size_t)row*K + gcol),
      (__attribute__((address_space(3))) void*)(&Bs3[slot][ldsoff]), 16, 0, 0);
  };

  // prologue: tiles 0 and 1 fully staged (8 loads in flight)
  stage_chunk(0, 0, 0); stage_chunk(0, 0, 1);
  if (ntk > 1) { stage_chunk(1, 1, 0); stage_chunk(1, 1, 1); }

  for (int t = 0; t < ntk; ++t) {
    const int cur = t % 3;
    // entry: wait for tile t only (t+1 stays in flight across the barrier)
    if (t + 1 < ntk) asm volatile("s_waitcnt vmcnt(4)" ::: "memory");
    else             asm volatile("s_waitcnt vmcnt(0)" ::: "memory");
    __builtin_amdgcn_sched_barrier(0);
    __builtin_amdgcn_s_barrier();
    __builtin_amdgcn_sched_barrier(0);

    const bf16* Ab = As3[cur];
    const bf16* Bb = Bs3[cur];

    // ---- phase 0: read b[0..3], a[0..3]; stage chunk 0 of t+2; 16 MFMA ----
    short8v a0[4], b[4];
    #pragma unroll
    for (int f = 0; f < 4; ++f) {
      int r = wr*128 + f*16 + fr;
      a0[f] = *(const short8v*)(Ab + r*32 + (kc ^ ((r >> 1) & 3))*8);
    }
    #pragma unroll
    for (int f = 0; f < 4; ++f) {
      int r = wc*64 + f*16 + fr;
      b[f] = *(const short8v*)(Bb + r*32 + (kc ^ ((r >> 1) & 3))*8);
    }
    if (t + 2 < ntk) stage_chunk(t + 2, (t + 2) % 3, 0);
    asm volatile("s_waitcnt lgkmcnt(0)" ::: "memory");
    __builtin_amdgcn_sched_barrier(0);
    __builtin_amdgcn_s_setprio(1);
    #pragma unroll
    for (int f = 0; f < 4; ++f)
      #pragma unroll
      for (int j = 0; j < 4; ++j)
        acc[f][j] = __builtin_amdgcn_mfma_f32_16x16x32_bf16(a0[f], b[j], acc[f][j], 0, 0, 0);
    __builtin_amdgcn_s_setprio(0);
    __builtin_amdgcn_sched_barrier(0);
    __builtin_amdgcn_s_barrier();
    __builtin_amdgcn_sched_barrier(0);

    // ---- phase 1: read a[4..7]; stage chunk 1 of t+2; 16 MFMA ----
    short8v a1[4];
    #pragma unroll
    for (int f = 0; f < 4; ++f) {
      int r = wr*128 + (f + 4)*16 + fr;
      a1[f] = *(const short8v*)(Ab + r*32 + (kc ^ ((r >> 1) & 3))*8);
    }
    if (t + 2 < ntk) stage_chunk(t + 2, (t + 2) % 3, 1);
    asm volatile("s_waitcnt lgkmcnt(0)" ::: "memory");
    __builtin_amdgcn_sched_barrier(0);
    __builtin_amdgcn_s_setprio(1);
    #pragma unroll
    for (int f = 0; f < 4; ++f)
      #pragma unroll
      for (int j = 0; j < 4; ++j)
        acc[f + 4][j] = __builtin_amdgcn_mfma_f32_16x16x32_bf16(a1[f], b[j], acc[f + 4][j], 0, 0, 0);
    __builtin_amdgcn_s_setprio(0);
    __builtin_amdgcn_sched_barrier(0);
    __builtin_amdgcn_s_barrier();   // also serves as next iteration's entry sync
    __builtin_amdgcn_sched_barrier(0);
  }

  const int cn = lane & 15, rq = lane >> 4;
  #pragma unroll
  for (int f = 0; f < 8; ++f) {
    #pragma unroll
    for (int j = 0; j < 4; ++j) {
      #pragma unroll
      for (int rr = 0; rr < 4; ++rr) {
        int row = bm + wr*128 + f*16 + rq*4 + rr;
        int col = bn + wc*64 + j*16 + cn;
        size_t off = (size_t)row*N + col;
        if constexpr (OUTBF) ((bf16*)C)[off] = __float2bfloat16(acc[f][j][rr]);
        else                 ((float*)C)[off] = acc[f][j][rr];
      }
    }
  }
}

// ------- in-place silu-mul over fused gu buffer: gu[:, :4096] = silu(g)*u ---
__global__ __launch_bounds__(256) void k_silumul_gu(bf16* __restrict__ gu) {
  int i = blockIdx.x*256 + threadIdx.x;     // over NT*4096/8
  if (i >= NT*512) return;
  int row = i >> 9;
  int c8 = (i & 511)*8;
  unsigned short* p = (unsigned short*)gu + (size_t)row*8192 + c8;
  short8v g = *(const short8v*)p;
  short8v u = *(const short8v*)(p + 4096);
  short8v o;
  #pragma unroll
  for (int j = 0; j < 8; ++j) {
    float gf = b2f((unsigned short)g[j]);
    float uf = b2f((unsigned short)u[j]);
    o[j] = (short)f2bu(gf / (1.0f + expf(-gf)) * uf);
  }
  *(short8v*)p = o;
}

// ---------------- flash attention: MFMA, online softmax --------------------
__global__ __launch_bounds__(256) void k_fattn(const bf16* __restrict__ qkvb,
    bf16* __restrict__ outb) {
  const unsigned short* qkv = (const unsigned short*)qkvb;
  const int qt = 15 - blockIdx.x;
  const int h = blockIdx.y, b = blockIdx.z;
  const int tid = threadIdx.x, lane = tid & 63, w = tid >> 6;
  const int g = lane >> 4, qn = lane & 15;

  __shared__ unsigned short Ks[64*64];
  __shared__ unsigned short Vt[64*64];
  __shared__ unsigned short Ps[4*16*64];

  const int q0 = qt * 64;
  const int qw0 = q0 + w*16;

  short8v qf[2];
  {
    const unsigned short* qp = qkv + ((size_t)(b*S_ + qw0 + qn))*3072 + h*DK_ + g*8;
    qf[0] = *(const short8v*)qp;
    qf[1] = *(const short8v*)(qp + 32);
  }

  floatx4 o_acc[4] = {};
  float m_run = -1e30f, l_run = 0.f;

  const int ntile = qt + 1;
  for (int it = 0; it < ntile; ++it) {
    const int t0 = it*64;

    {
      const int trow = w*8 + (lane>>3);
      const int d16 = (lane&7) ^ (trow&7);
      #pragma unroll
      for (int c = 0; c < 2; ++c) {
        const unsigned short* gk = qkv + ((size_t)(b*S_ + t0 + c*32 + trow))*3072
                                   + 1024 + h*DK_ + d16*8;
        __builtin_amdgcn_global_load_lds(
          (const __attribute__((address_space(1))) void*)gk,
          (__attribute__((address_space(3))) void*)(Ks + c*2048 + w*512), 16, 0, 0);
      }
    }
    #pragma unroll
    for (int c = 0; c < 2; ++c) {
      int idx = c*256 + tid;
      int t = idx >> 3;
      int d0 = (idx & 7)*8;
      short8v vv = *(const short8v*)(qkv + ((size_t)(b*S_ + t0 + t))*3072 + 2048 + h*DK_ + d0);
      #pragma unroll
      for (int jj = 0; jj < 8; ++jj) {
        int d = d0 + jj;
        int slot = ((t>>3) ^ (d&7) ^ ((d>>3)&7)) & 7;
        Vt[d*64 + slot*8 + (t&7)] = (unsigned short)vv[jj];
      }
    }
    __syncthreads();

    floatx4 st[4];
    #pragma unroll
    for (int f = 0; f < 4; ++f) {
      st[f] = (floatx4){0.f,0.f,0.f,0.f};
      int t = f*16 + qn;
      #pragma unroll
      for (int ks = 0; ks < 2; ++ks) {
        int slot = ((ks*4 + g) ^ (t&7)) & 7;
        short8v kf = *(const short8v*)(Ks + t*64 + slot*8);
        st[f] = __builtin_amdgcn_mfma_f32_16x16x32_bf16(kf, qf[ks], st[f], 0,0,0);
      }
    }

    const bool diag = (it == qt);
    float sc[4][4];
    #pragma unroll
    for (int f = 0; f < 4; ++f)
      #pragma unroll
      for (int r = 0; r < 4; ++r) {
        float v = st[f][r]*0.125f;
        if (diag) {
          int tl = f*16 + g*4 + r;
          if (tl > w*16 + qn) v = -1e30f;
        }
        sc[f][r] = v;
      }
    float mx = -1e30f;
    #pragma unroll
    for (int f = 0; f < 4; ++f)
      #pragma unroll
      for (int r = 0; r < 4; ++r) mx = fmaxf(mx, sc[f][r]);
    mx = fmaxf(mx, __shfl_xor(mx, 16));
    mx = fmaxf(mx, __shfl_xor(mx, 32));
    float m_new = fmaxf(m_run, mx);
    float corr = __expf(m_run - m_new);
    m_run = m_new;
    float ls = 0.f;
    #pragma unroll
    for (int f = 0; f < 4; ++f)
      #pragma unroll
      for (int r = 0; r < 4; ++r) {
        float p = __expf(sc[f][r] - m_new);
        sc[f][r] = p;
        ls += p;
      }
    ls += __shfl_xor(ls, 16);
    ls += __shfl_xor(ls, 32);
    l_run = l_run*corr + ls;

    unsigned short* Pw = Ps + w*1024;
    #pragma unroll
    for (int f = 0; f < 4; ++f) {
      unsigned int lo = (unsigned int)f2bu(sc[f][0]) | ((unsigned int)f2bu(sc[f][1]) << 16);
      unsigned int hi = (unsigned int)f2bu(sc[f][2]) | ((unsigned int)f2bu(sc[f][3]) << 16);
      int c16 = f*2 + (g>>1);
      int slot = (c16 ^ (qn&7)) & 7;
      *(uint2*)((char*)Pw + qn*128 + slot*16 + (g&1)*8) = make_uint2(lo, hi);
    }

    #pragma unroll
    for (int r = 0; r < 4; ++r) {
      float cr = __shfl(corr, g*4 + r);
      #pragma unroll
      for (int fd = 0; fd < 4; ++fd) o_acc[fd][r] *= cr;
    }

    short8v pf[2];
    #pragma unroll
    for (int ks = 0; ks < 2; ++ks) {
      int slot = ((ks*4 + g) ^ (qn&7)) & 7;
      pf[ks] = *(const short8v*)(Pw + qn*64 + slot*8);
    }
    #pragma unroll
    for (int fd = 0; fd < 4; ++fd) {
      int d = fd*16 + qn;
      #pragma unroll
      for (int ks = 0; ks < 2; ++ks) {
        int slot = ((ks*4 + g) ^ (d&7) ^ ((d>>3)&7)) & 7;
        short8v vf = *(const short8v*)(Vt + d*64 + slot*8);
        o_acc[fd] = __builtin_amdgcn_mfma_f32_16x16x32_bf16(pf[ks], vf, o_acc[fd], 0,0,0);
      }
    }
    __syncthreads();
  }

  float linv = 1.0f / l_run;
  #pragma unroll
  for (int r = 0; r < 4; ++r) {
    float li = __shfl(linv, g*4 + r);
    int row = qw0 + g*4 + r;
    bf16* op = outb + (size_t)(b*S_ + row)*D_ + h*DK_ + qn;
    #pragma unroll
    for (int fd = 0; fd < 4; ++fd)
      op[fd*16] = __float2bfloat16(o_acc[fd][r] * li);
  }
}

extern "C" void kernel_launch(void* const* d_in, const int* in_sizes, int n_in,
                              void* d_out, int out_size, void* d_ws, size_t ws_size,
                              hipStream_t stream) {
  (void)in_sizes; (void)n_in; (void)out_size; (void)ws_size;
  const int*   ids  = (const int*)d_in[0];
  const float* emb  = (const float*)d_in[1];
  const float* wqkv = (const float*)d_in[2];
  const float* wo   = (const float*)d_in[3];
  const float* n1   = (const float*)d_in[4];
  const float* n2   = (const float*)d_in[5];
  const float* wg   = (const float*)d_in[6];
  const float* wu   = (const float*)d_in[7];
  const float* wd   = (const float*)d_in[8];
  const float* fnw  = (const float*)d_in[9];
  float* out = (float*)d_out;

  char* ws = (char*)d_ws;
  float* x      = (float*)ws;                                   ws += (size_t)NT*D_*4;
  bf16*  nx_bf  = (bf16*)ws;                                    ws += (size_t)NT*D_*2;
  bf16*  att_bf = (bf16*)ws;                                    ws += (size_t)NT*D_*2;
  bf16*  shared = (bf16*)ws;                                    ws += (size_t)NT*8192*2;
  bf16*  emb_bf = (bf16*)ws;                                    ws += (size_t)V_*D_*2;
  bf16*  qkv_bf = shared;                 // NT*3D, dead before gu written
  bf16*  gu     = shared;                 // NT*8192 (g | u), silu'd in place

  bf16* wsc = (bf16*)d_out;
  bf16* wqkv_t = wsc;                                  // L*3D*D
  bf16* wo_t   = wqkv_t + (size_t)L_*3*D_*D_;          // L*D*D
  bf16* wgu_t  = wo_t   + (size_t)L_*D_*D_;            // L*8192*1024 (gate|up)
  bf16* wd_t   = wgu_t  + (size_t)L_*2*D_*FF_;         // L*D*FF

  dim3 blk(256);

  {
    dim3 gq(3*D_/64, D_/64, L_);
    k_transpose_cast<<<gq, blk, 0, stream>>>(wqkv, wqkv_t, D_, 3*D_,
        (size_t)D_*3*D_, (size_t)3*D_*D_);
    dim3 go(D_/64, D_/64, L_);
    k_transpose_cast<<<go, blk, 0, stream>>>(wo, wo_t, D_, D_,
        (size_t)D_*D_, (size_t)D_*D_);
    dim3 gg(FF_/64, D_/64, L_);
    k_transpose_cast<<<gg, blk, 0, stream>>>(wg, wgu_t, D_, FF_,
        (size_t)D_*FF_, (size_t)2*D_*FF_);
    k_transpose_cast<<<gg, blk, 0, stream>>>(wu, wgu_t + (size_t)FF_*D_, D_, FF_,
        (size_t)D_*FF_, (size_t)2*D_*FF_);
    dim3 gdn(D_/64, FF_/64, L_);
    k_transpose_cast<<<gdn, blk, 0, stream>>>(wd, wd_t, FF_, D_,
        (size_t)FF_*D_, (size_t)D_*FF_);
  }
  k_cast4<<<(V_*D_/4 + 255)/256, blk, 0, stream>>>(emb, emb_bf, V_*D_/4);

  k_embed<<<(NT*D_+255)/256, blk, 0, stream>>>(ids, emb, x);

  for (int l = 0; l < L_; ++l) {
    k_rms<<<NT, blk, 0, stream>>>(x, n1 + (size_t)l*D_, nx_bf);
    k_mfma_gemm_bt<2,true><<<remap_grid(NT,3*D_), blk, 0, stream>>>(
        nx_bf, wqkv_t + (size_t)l*3*D_*D_, nullptr, qkv_bf, NT, 3*D_, D_);
    dim3 gattn(16, H_, B_);
    k_fattn<<<gattn, blk, 0, stream>>>(qkv_bf, att_bf);
    k_gemm_64<<<(NT/64)*(D_/128), blk, 0, stream>>>(
        att_bf, wo_t + (size_t)l*D_*D_, x, x, NT, D_, D_, D_);
    k_rms<<<NT, blk, 0, stream>>>(x, n2 + (size_t)l*D_, nx_bf);
    k_gemm256<true><<<(NT/256)*(2*FF_/256), dim3(512), 0, stream>>>(
        nx_bf, wgu_t + (size_t)l*2*D_*FF_, gu, NT, 2*FF_, D_);
    k_silumul_gu<<<(NT*512 + 255)/256, blk, 0, stream>>>(gu);
    k_gemm_64<<<(NT/64)*(D_/128), blk, 0, stream>>>(
        gu, wd_t + (size_t)l*D_*FF_, x, x, NT, D_, FF_, 2*FF_);
  }
  k_rms<<<NT, blk, 0, stream>>>(x, fnw, nx_bf);
  k_gemm256<false><<<(NT/256)*(V_/256), dim3(512), 0, stream>>>(
      nx_bf, emb_bf, out, NT, V_, D_);
}